// Round 6
// baseline (205.912 us; speedup 1.0000x reference)
//
#include <hip/hip_runtime.h>
#include <hip/hip_bf16.h>

#define NN   100000
#define KNB  32
#define DIN  256
#define DOUT 128
#define SLICE_D 16          // douts per h-slice (16 bf16 = 32 B rows)
#define NSLICE 8            // 8 * 16 == DOUT

typedef __attribute__((ext_vector_type(8))) short short8;    // 8 x bf16
typedef __attribute__((ext_vector_type(4))) float f32x4;     // 4 x f32
typedef __attribute__((ext_vector_type(4))) unsigned u32x4;  // 16 B
typedef __attribute__((ext_vector_type(4))) int i32x4;       // 16 B

// v_cvt_pk_bf16_f32: packs 2 f32 -> 2 bf16 (RTNE) in one VALU op (no builtin).
__device__ __forceinline__ unsigned pk2(float a, float b) {
    unsigned r;
    asm("v_cvt_pk_bf16_f32 %0, %1, %2" : "=v"(r) : "v"(a), "v"(b));
    return r;
}

__device__ __forceinline__ short8 cvt8(f32x4 a, f32x4 b) {
    u32x4 t;
    t[0] = pk2(a[0], a[1]);
    t[1] = pk2(a[2], a[3]);
    t[2] = pk2(b[0], b[1]);
    t[3] = pk2(b[2], b[3]);
    return __builtin_bit_cast(short8, t);
}

// ---------------------------------------------------------------------------
// Kernel 0: W [DIN][DOUT] f32  ->  Wt [DOUT][DIN] bf16 (transposed + converted)
// ---------------------------------------------------------------------------
__global__ void wt_conv(const float* __restrict__ W, unsigned short* __restrict__ Wt) {
    int t = blockIdx.x * 256 + threadIdx.x;   // 0 .. 32767
    int d = t >> 8;                           // dout
    int k = t & 255;                          // din
    float v = W[(size_t)k * DOUT + d];
    Wt[t] = (unsigned short)(pk2(v, v) & 0xffffu);
}

// ---------------------------------------------------------------------------
// Kernel 1: h = relu(feats @ W + b), stored bf16 in SLICED layout:
//   hs[c][n][16]  (c = dout/16) -> each slice is 3.2 MB (L2-resident later).
// Operand-swapped MFMA: A = Wt (M = DOUT), B = feats^T (N = nodes).
// One wave per block, 32 nodes; 3125*32 == NN -> no bounds checks.
// Slice store: per (mf,nf) instruction = 16 nodes x 32 B contiguous = 512 B
// fully coalesced (better than the old 256B-strided row-major stores).
// ---------------------------------------------------------------------------
__global__ __launch_bounds__(64) void gemm_relu(
        const float* __restrict__ feats, const unsigned short* __restrict__ Wt,
        const float* __restrict__ bias, unsigned short* __restrict__ h) {
    const int lane = threadIdx.x;             // 0..63
    const int l16  = lane & 15;
    const int lq   = lane >> 4;
    const int nodeBase = blockIdx.x * 32;     // 3125 * 32 == 100000

    f32x4 acc[8][2];
    #pragma unroll
    for (int mf = 0; mf < 8; ++mf) { acc[mf][0] = (f32x4)0.f; acc[mf][1] = (f32x4)0.f; }

    const float* f0p = feats + (size_t)(nodeBase + l16) * DIN + lq * 8;
    const float* f1p = f0p + 16 * DIN;
    const unsigned short* wp = Wt + l16 * DIN + lq * 8;

    #pragma unroll
    for (int ks = 0; ks < 8; ++ks) {
        f32x4 a0 = *(const f32x4*)(f0p + ks * 32);
        f32x4 a1 = *(const f32x4*)(f0p + ks * 32 + 4);
        f32x4 c0 = *(const f32x4*)(f1p + ks * 32);
        f32x4 c1 = *(const f32x4*)(f1p + ks * 32 + 4);
        short8 bfrag0 = cvt8(a0, a1);
        short8 bfrag1 = cvt8(c0, c1);
        #pragma unroll
        for (int mf = 0; mf < 8; ++mf) {
            short8 a = *(const short8*)(wp + mf * 16 * DIN + ks * 32);
            acc[mf][0] = __builtin_amdgcn_mfma_f32_16x16x32_bf16(a, bfrag0, acc[mf][0], 0, 0, 0);
            acc[mf][1] = __builtin_amdgcn_mfma_f32_16x16x32_bf16(a, bfrag1, acc[mf][1], 0, 0, 0);
        }
    }

    // Epilogue: bias + relu + pack 4 bf16 -> 8 B store into slice mf.
    // D layout: col (node) = lane&15, row (dout) = (lane>>4)*4 + reg  [m89]
    #pragma unroll
    for (int mf = 0; mf < 8; ++mf) {
        int dbase = mf * 16 + lq * 4;                    // absolute dout
        f32x4 bv = *(const f32x4*)(bias + dbase);
        unsigned short* hslice = h + (size_t)mf * NN * SLICE_D;
        #pragma unroll
        for (int nf = 0; nf < 2; ++nf) {
            int node = nodeBase + nf * 16 + l16;
            f32x4 v = acc[mf][nf];
            float v0 = fmaxf(v[0] + bv[0], 0.f);
            float v1 = fmaxf(v[1] + bv[1], 0.f);
            float v2 = fmaxf(v[2] + bv[2], 0.f);
            float v3 = fmaxf(v[3] + bv[3], 0.f);
            uint2 st = make_uint2(pk2(v0, v1), pk2(v2, v3));
            *(uint2*)(hslice + (size_t)node * SLICE_D + lq * 4) = st;
        }
    }
}

// ---------------------------------------------------------------------------
// Kernel 2 (x8 dispatches): out[n, c*16 : c*16+16] = mean_k hs_c[edge[n][k]]
// hs_c is ONE 3.2 MB slice -> L2-resident per XCD during the dispatch.
// 4 lanes per node (sub = douts sub*4..+4 of the slice). Each lane holds 8
// of the node's edges in registers; __shfl broadcasts within the 4-lane group.
// Edge loads are CACHED (not NT): the same per-XCD edge slice is re-read by
// all 8 dispatches and should stay L2-resident after pass 0.
// ---------------------------------------------------------------------------
__global__ __launch_bounds__(256) void gather_slice(
        const int* __restrict__ edge, const unsigned short* __restrict__ hs,
        float* __restrict__ out_c) {
    const int tid  = threadIdx.x;
    const int sub  = tid & 3;                 // which 4-dout group of the slice
    const int node = blockIdx.x * 64 + (tid >> 2);
    const int lane = tid & 63;
    const int gbase = lane & ~3;              // 4-lane group base within wave
    const bool valid = node < NN;
    const int nc = valid ? node : NN - 1;

    // lane's 8 edges: k in [sub*8, sub*8+8)
    const i32x4* ep = (const i32x4*)(edge + (size_t)nc * KNB + sub * 8);
    i32x4 ea = ep[0];
    i32x4 eb = ep[1];

    float a0 = 0.f, a1 = 0.f, a2 = 0.f, a3 = 0.f;

    #define EV(k) (((k) & 7) < 4 ? ea[(k) & 3] : eb[(k) & 3])
    #define GK(k) do { \
        int se = __shfl(EV(k), gbase + ((k) >> 3), 64); \
        uint2 v = *(const uint2*)(hs + (size_t)se * SLICE_D + sub * 4); \
        a0 += __uint_as_float(v.x << 16); \
        a1 += __uint_as_float(v.x & 0xffff0000u); \
        a2 += __uint_as_float(v.y << 16); \
        a3 += __uint_as_float(v.y & 0xffff0000u); } while (0)

    GK( 0); GK( 1); GK( 2); GK( 3); GK( 4); GK( 5); GK( 6); GK( 7);
    GK( 8); GK( 9); GK(10); GK(11); GK(12); GK(13); GK(14); GK(15);
    GK(16); GK(17); GK(18); GK(19); GK(20); GK(21); GK(22); GK(23);
    GK(24); GK(25); GK(26); GK(27); GK(28); GK(29); GK(30); GK(31);

    #undef GK
    #undef EV

    if (valid) {
        const float sc = 1.f / KNB;
        f32x4 o = { a0 * sc, a1 * sc, a2 * sc, a3 * sc };
        // 4-lane group writes 64 B contiguous (one full line of out's slice col)
        __builtin_nontemporal_store(o, (f32x4*)(out_c + (size_t)node * DOUT + sub * 4));
    }
}

// ---------------------------------------------------------------------------
extern "C" void kernel_launch(void* const* d_in, const int* in_sizes, int n_in,
                              void* d_out, int out_size, void* d_ws, size_t ws_size,
                              hipStream_t stream) {
    const float* feats = (const float*)d_in[0];   // [100000,256] f32
    const int*   edge  = (const int*)d_in[1];     // [100000,32] i32
    const float* W     = (const float*)d_in[2];   // [256,128] f32
    const float* b     = (const float*)d_in[3];   // [128] f32
    float* out = (float*)d_out;                   // [100000,128] f32

    unsigned short* Wt = (unsigned short*)d_ws;                    // 64 KB
    unsigned short* h  = (unsigned short*)((char*)d_ws + 65536);   // 25.6 MB sliced

    wt_conv<<<128, 256, 0, stream>>>(W, Wt);
    gemm_relu<<<NN / 32, 64, 0, stream>>>(feats, Wt, b, h);
    for (int c = 0; c < NSLICE; ++c) {
        gather_slice<<<(NN + 63) / 64, 256, 0, stream>>>(
            edge, h + (size_t)c * NN * SLICE_D, out + c * SLICE_D);
    }
}

// Round 7
// 165.439 us; speedup vs baseline: 1.2446x; 1.2446x over previous
//
#include <hip/hip_runtime.h>
#include <hip/hip_bf16.h>

#define NN   100000
#define KNB  32
#define DIN  256
#define DOUT 128
#define BNODES 128           // nodes per gemm block
#define BK 64                // din per K-step (f32)

typedef __attribute__((ext_vector_type(8))) short short8;    // 8 x bf16
typedef __attribute__((ext_vector_type(4))) float f32x4;     // 4 x f32
typedef __attribute__((ext_vector_type(4))) unsigned u32x4;  // 16 B
typedef __attribute__((ext_vector_type(2))) int i32x2;       // 8 B

// v_cvt_pk_bf16_f32: packs 2 f32 -> 2 bf16 (RTNE) in one VALU op (no builtin).
__device__ __forceinline__ unsigned pk2(float a, float b) {
    unsigned r;
    asm("v_cvt_pk_bf16_f32 %0, %1, %2" : "=v"(r) : "v"(a), "v"(b));
    return r;
}

__device__ __forceinline__ short8 cvt8(f32x4 a, f32x4 b) {
    u32x4 t;
    t[0] = pk2(a[0], a[1]);
    t[1] = pk2(a[2], a[3]);
    t[2] = pk2(b[0], b[1]);
    t[3] = pk2(b[2], b[3]);
    return __builtin_bit_cast(short8, t);
}

// async global->LDS, 16 B per lane. LDS dest must be linear (base + lane*16).
__device__ __forceinline__ void load_lds16(const float* g, float* l) {
    __builtin_amdgcn_global_load_lds(
        (const __attribute__((address_space(1))) void*)g,
        (__attribute__((address_space(3))) void*)l, 16, 0, 0);
}

// ---------------------------------------------------------------------------
// Kernel 0: W [DIN][DOUT] f32  ->  Wt [DOUT][DIN] bf16 (transposed + converted)
// ---------------------------------------------------------------------------
__global__ void wt_conv(const float* __restrict__ W, unsigned short* __restrict__ Wt) {
    int t = blockIdx.x * 256 + threadIdx.x;   // 0 .. 32767
    int d = t >> 8;                           // dout
    int k = t & 255;                          // din
    float v = W[(size_t)k * DOUT + d];
    Wt[t] = (unsigned short)(pk2(v, v) & 0xffffu);
}

// ---------------------------------------------------------------------------
// Kernel 1: h = relu(feats @ W + b), stored bf16 row-major [n][128].
// R6 post-mortem: reg-path version was latency-bound (MfmaUtil 3.4%, ~0.7 KB
// in flight/CU). Fix: canonical LDS pipeline — feats f32 staged via
// global_load_lds width=16 (in-flight bytes live in the LDS queue, not VGPRs),
// BK=64 double-buffered (64 KB LDS -> 2 blocks/CU), 2-phase loop.
// LDS swizzle (rule #21, both sides): chunk16 ^= (node&15) applied to the
// GLOBAL source during staging (dest stays lane-linear) and to the ds_read
// address. Quarter-wave: 16 lanes hit 16 distinct chunks -> 2-way min (free).
// Operand-swapped MFMA: A = Wt (M = DOUT), B = feats^T (N = nodes).
// ---------------------------------------------------------------------------
__global__ __launch_bounds__(256) void gemm_relu(
        const float* __restrict__ feats, const unsigned short* __restrict__ Wt,
        const float* __restrict__ bias, unsigned short* __restrict__ h) {
    __shared__ float sbuf[2][BNODES * BK];    // 2 x 32 KB

    const int lane = threadIdx.x & 63;
    const int w    = threadIdx.x >> 6;
    const int l16  = lane & 15;
    const int lq   = lane >> 4;
    const int blockBase = blockIdx.x * BNODES;

    f32x4 acc[8][2];
    #pragma unroll
    for (int mf = 0; mf < 8; ++mf) { acc[mf][0] = (f32x4)0.f; acc[mf][1] = (f32x4)0.f; }

    const unsigned short* wp = Wt + l16 * DIN + lq * 8;

    // Stage K-step t (BK=64 f32 per node, 128 nodes = 32 KB) into sbuf[pb].
    // Wave w covers slots w*8..w*8+7; instr j writes nodes slot*4..+4 linearly.
    auto stage = [&](int t, int pb) {
        #pragma unroll
        for (int j = 0; j < 8; ++j) {
            int slot = w * 8 + j;                   // 0..31
            int nloc = slot * 4 + (lane >> 4);      // 0..127
            int ng   = blockBase + nloc;
            ng = ng < NN ? ng : NN - 1;             // clamp (stores predicated)
            int cdest = lane & 15;                  // 16B chunk within node row
            int csrc  = cdest ^ (nloc & 15);        // pre-swizzled global source
            load_lds16(feats + (size_t)ng * DIN + t * BK + csrc * 4,
                       &sbuf[pb][nloc * BK + cdest * 4]);
        }
    };

    stage(0, 0);
    asm volatile("s_waitcnt vmcnt(0)" ::: "memory");
    __syncthreads();

    #pragma unroll
    for (int t = 0; t < DIN / BK; ++t) {            // 4 K-steps
        const int pb = t & 1;
        if (t < DIN / BK - 1) stage(t + 1, pb ^ 1);

        const float* buf = sbuf[pb];
        #pragma unroll
        for (int ks = 0; ks < 2; ++ks) {            // two 32-din MFMA chunks
            short8 bf0, bf1;
            {
                const float* row = buf + (w * 32 + l16) * BK;
                f32x4 x0 = *(const f32x4*)(row + ((ks * 8 + 2 * lq)     ^ l16) * 4);
                f32x4 x1 = *(const f32x4*)(row + ((ks * 8 + 2 * lq + 1) ^ l16) * 4);
                bf0 = cvt8(x0, x1);
            }
            {
                const float* row = buf + (w * 32 + 16 + l16) * BK;
                f32x4 x0 = *(const f32x4*)(row + ((ks * 8 + 2 * lq)     ^ l16) * 4);
                f32x4 x1 = *(const f32x4*)(row + ((ks * 8 + 2 * lq + 1) ^ l16) * 4);
                bf1 = cvt8(x0, x1);
            }
            #pragma unroll
            for (int mf = 0; mf < 8; ++mf) {
                short8 a = *(const short8*)(wp + mf * 16 * DIN + (t * 2 + ks) * 32);
                acc[mf][0] = __builtin_amdgcn_mfma_f32_16x16x32_bf16(a, bf0, acc[mf][0], 0, 0, 0);
                acc[mf][1] = __builtin_amdgcn_mfma_f32_16x16x32_bf16(a, bf1, acc[mf][1], 0, 0, 0);
            }
        }

        if (t < DIN / BK - 1) {
            asm volatile("s_waitcnt vmcnt(0)" ::: "memory");
            __syncthreads();
        }
    }

    // Epilogue: bias + relu + pack 4 bf16 -> 8 B store (row-major h).
    // D layout: col (node) = lane&15, row (dout) = (lane>>4)*4 + reg  [m89]
    #pragma unroll
    for (int mf = 0; mf < 8; ++mf) {
        int dbase = mf * 16 + lq * 4;
        f32x4 bv = *(const f32x4*)(bias + dbase);
        #pragma unroll
        for (int nf = 0; nf < 2; ++nf) {
            int node = blockBase + w * 32 + nf * 16 + l16;
            if (node < NN) {
                f32x4 v = acc[mf][nf];
                float v0 = fmaxf(v[0] + bv[0], 0.f);
                float v1 = fmaxf(v[1] + bv[1], 0.f);
                float v2 = fmaxf(v[2] + bv[2], 0.f);
                float v3 = fmaxf(v[3] + bv[3], 0.f);
                uint2 st = make_uint2(pk2(v0, v1), pk2(v2, v3));
                *(uint2*)(h + (size_t)node * DOUT + dbase) = st;
            }
        }
    }
}

// ---------------------------------------------------------------------------
// Kernel 2: out[n] = mean_k h_bf16[edge[n][k]]   (R5 version, 107 µs, BW-bound)
// Quarter-wave (16 lanes) per node, 16 B dwordx4 per lane.
// 8-deep NAMED-register pipeline (R3: array-indexed bufs spilled to scratch).
// ---------------------------------------------------------------------------
__global__ __launch_bounds__(256) void gather_mean(
        const int* __restrict__ edge, const unsigned short* __restrict__ h,
        float* __restrict__ out) {
    const int q = threadIdx.x & 15;
    const int n = blockIdx.x * 16 + (threadIdx.x >> 4);   // 6250*16 == NN exactly

    i32x2 e2 = __builtin_nontemporal_load((const i32x2*)(edge + n * KNB + q * 2));

    float s0=0,s1=0,s2=0,s3=0,s4=0,s5=0,s6=0,s7=0;

    #define ROW(k) ((size_t)((k) < 16 ? __shfl(e2[0], (k), 16) \
                                      : __shfl(e2[1], (k) - 16, 16)) * DOUT)
    #define LD(k)  (*(const u32x4*)(h + ROW(k) + q * 8))
    #define ACC(v) do { \
        s0 += __uint_as_float((v)[0] << 16); \
        s1 += __uint_as_float((v)[0] & 0xffff0000u); \
        s2 += __uint_as_float((v)[1] << 16); \
        s3 += __uint_as_float((v)[1] & 0xffff0000u); \
        s4 += __uint_as_float((v)[2] << 16); \
        s5 += __uint_as_float((v)[2] & 0xffff0000u); \
        s6 += __uint_as_float((v)[3] << 16); \
        s7 += __uint_as_float((v)[3] & 0xffff0000u); } while (0)
    #define STEP(k, B) do { u32x4 v_ = (B); \
        if ((k) + 8 < KNB) (B) = LD((k) + 8); \
        ACC(v_); } while (0)

    u32x4 b0 = LD(0), b1 = LD(1), b2 = LD(2), b3 = LD(3);
    u32x4 b4 = LD(4), b5 = LD(5), b6 = LD(6), b7 = LD(7);

    STEP( 0, b0); STEP( 1, b1); STEP( 2, b2); STEP( 3, b3);
    STEP( 4, b4); STEP( 5, b5); STEP( 6, b6); STEP( 7, b7);
    STEP( 8, b0); STEP( 9, b1); STEP(10, b2); STEP(11, b3);
    STEP(12, b4); STEP(13, b5); STEP(14, b6); STEP(15, b7);
    STEP(16, b0); STEP(17, b1); STEP(18, b2); STEP(19, b3);
    STEP(20, b4); STEP(21, b5); STEP(22, b6); STEP(23, b7);
    STEP(24, b0); STEP(25, b1); STEP(26, b2); STEP(27, b3);
    STEP(28, b4); STEP(29, b5); STEP(30, b6); STEP(31, b7);

    #undef STEP
    #undef ACC
    #undef LD
    #undef ROW

    const float sc = 1.f / KNB;
    f32x4 o0 = { s0 * sc, s1 * sc, s2 * sc, s3 * sc };
    f32x4 o1 = { s4 * sc, s5 * sc, s6 * sc, s7 * sc };
    float* op = out + (size_t)n * DOUT + q * 8;
    __builtin_nontemporal_store(o0, (f32x4*)op);
    __builtin_nontemporal_store(o1, (f32x4*)(op + 4));
}

// ---------------------------------------------------------------------------
extern "C" void kernel_launch(void* const* d_in, const int* in_sizes, int n_in,
                              void* d_out, int out_size, void* d_ws, size_t ws_size,
                              hipStream_t stream) {
    const float* feats = (const float*)d_in[0];   // [100000,256] f32
    const int*   edge  = (const int*)d_in[1];     // [100000,32] i32
    const float* W     = (const float*)d_in[2];   // [256,128] f32
    const float* b     = (const float*)d_in[3];   // [128] f32
    float* out = (float*)d_out;                   // [100000,128] f32

    unsigned short* Wt = (unsigned short*)d_ws;                    // 64 KB
    unsigned short* h  = (unsigned short*)((char*)d_ws + 65536);   // 25.6 MB row-major

    wt_conv<<<128, 256, 0, stream>>>(W, Wt);
    gemm_relu<<<(NN + BNODES - 1) / BNODES, 256, 0, stream>>>(feats, Wt, b, h);
    gather_mean<<<NN / 16, 256, 0, stream>>>(edge, h, out);
}